// Round 2
// baseline (401.501 us; speedup 1.0000x reference)
//
#include <hip/hip_runtime.h>
#include <math.h>

#define EPSF   1e-8f
#define CLAMPF 0.99999f   // 1 - 1e-5 (f32)

// ---------------- helpers ----------------
__device__ __forceinline__ float wave_sum64(float v) {
  v += __shfl_xor(v, 1, 64);
  v += __shfl_xor(v, 2, 64);
  v += __shfl_xor(v, 4, 64);
  v += __shfl_xor(v, 8, 64);
  v += __shfl_xor(v, 16, 64);
  v += __shfl_xor(v, 32, 64);
  return v;
}

// score(q,k) = -dist/sqrt(dk), dist = 2*atanh(n), n from mobius_add(-q,k) scalars
__device__ __forceinline__ float hyp_score(float q2, float k2, float dot) {
  float xy  = -dot;
  float A   = 1.f + 2.f*xy + k2;
  float Bc  = 1.f - q2;
  float num2 = A*A*q2 + Bc*Bc*k2 + 2.f*A*Bc*xy;
  float den  = fmaxf(1.f + 2.f*xy + q2*k2, EPSF);
  float nv   = sqrtf(fmaxf(num2, 0.f)) / den;
  nv = fminf(nv, CLAMPF);                    // clamp_to_ball + (1-EPS) clamp (latter = 1.0f, no-op)
  float dist = logf((1.f + nv) / (1.f - nv)); // == 2*atanh(nv)
  return dist * (-0.125f);                   // -dist / sqrt(64)
}

// ---------------- kernels ----------------

// bias_ball = expmap0(b) for bq (block 0) and bk (block 1); writes 520 floats each:
// [0..511]=bias_ball, [512]=||bias_ball||^2
__global__ __launch_bounds__(256) void bias_ball_kernel(const float* __restrict__ bq,
                                                        const float* __restrict__ bk,
                                                        float* __restrict__ bb) {
  const int which = blockIdx.x;
  const float* b = which ? bk : bq;
  float* o = bb + (size_t)which * 520;
  const int t = threadIdx.x;
  float2 v = ((const float2*)b)[t];
  __shared__ float red[4];
  float s = wave_sum64(v.x*v.x + v.y*v.y);
  if ((t & 63) == 0) red[t >> 6] = s;
  __syncthreads();
  float n2 = red[0] + red[1] + red[2] + red[3];
  float n  = sqrtf(n2);
  float nm = fmaxf(n, EPSF);
  float tt = fminf(nm, 15.f);
  float f  = tanhf(tt) / nm;
  float on = f * nm;
  if (on > CLAMPF) f *= CLAMPF / on;   // clamp_to_ball
  ((float2*)o)[t] = make_float2(f * v.x, f * v.y);
  if (t == 0) o[512] = f * f * n2;
}

// xe = logmap0(x), row-wise over d=512. One block per row.
__global__ __launch_bounds__(256) void logmap_kernel(const float* __restrict__ x,
                                                     float* __restrict__ xe) {
  const int row = blockIdx.x;
  const int t = threadIdx.x;
  float2 v = ((const float2*)(x + (size_t)row * 512))[t];
  __shared__ float red[4];
  float s = wave_sum64(v.x*v.x + v.y*v.y);
  if ((t & 63) == 0) red[t >> 6] = s;
  __syncthreads();
  float n2 = red[0] + red[1] + red[2] + red[3];
  float n  = sqrtf(n2);
  float nm = fmaxf(n, EPSF);
  float a  = fminf(nm, 1.0f);          // min(n, 1-1e-8) rounds to 1.0f in fp32
  float at = 0.5f * logf((1.f + a) / (1.f - a));
  float sc = at / nm;
  ((float2*)(xe + (size_t)row * 512))[t] = make_float2(v.x * sc, v.y * sc);
}

// out[m][n] = sum_k A[m][k]*W[n][k] (+ bias[n]).  M=4096 (grid.y*64), N=512 (grid.x*64), K=512.
__global__ __launch_bounds__(256) void gemm_nt_kernel(const float* __restrict__ A,
                                                      const float* __restrict__ W,
                                                      const float* __restrict__ bias,
                                                      float* __restrict__ out) {
  __shared__ float As[32][68];  // [k][m], stride 68 keeps 16B align + spreads banks
  __shared__ float Ws[32][68];  // [k][n]
  const int t  = threadIdx.x;
  const int bx = blockIdx.x, by = blockIdx.y;
  const int tx = t & 15, ty = t >> 4;
  const int r  = t >> 3, c4 = t & 7;
  float acc[4][4] = {{0.f}};
  const float* Abase = A + (size_t)(by * 64) * 512;
  const float* Wbase = W + (size_t)(bx * 64) * 512;
  for (int kt = 0; kt < 512; kt += 32) {
    __syncthreads();
    float4 a0 = *(const float4*)(Abase + (size_t)r        * 512 + kt + c4 * 4);
    float4 a1 = *(const float4*)(Abase + (size_t)(r + 32) * 512 + kt + c4 * 4);
    float4 w0 = *(const float4*)(Wbase + (size_t)r        * 512 + kt + c4 * 4);
    float4 w1 = *(const float4*)(Wbase + (size_t)(r + 32) * 512 + kt + c4 * 4);
    As[c4*4+0][r] = a0.x; As[c4*4+1][r] = a0.y; As[c4*4+2][r] = a0.z; As[c4*4+3][r] = a0.w;
    As[c4*4+0][r+32] = a1.x; As[c4*4+1][r+32] = a1.y; As[c4*4+2][r+32] = a1.z; As[c4*4+3][r+32] = a1.w;
    Ws[c4*4+0][r] = w0.x; Ws[c4*4+1][r] = w0.y; Ws[c4*4+2][r] = w0.z; Ws[c4*4+3][r] = w0.w;
    Ws[c4*4+0][r+32] = w1.x; Ws[c4*4+1][r+32] = w1.y; Ws[c4*4+2][r+32] = w1.z; Ws[c4*4+3][r+32] = w1.w;
    __syncthreads();
#pragma unroll
    for (int kk = 0; kk < 32; ++kk) {
      float4 a4 = *(const float4*)&As[kk][ty * 4];
      float4 w4 = *(const float4*)&Ws[kk][tx * 4];
      acc[0][0] += a4.x*w4.x; acc[0][1] += a4.x*w4.y; acc[0][2] += a4.x*w4.z; acc[0][3] += a4.x*w4.w;
      acc[1][0] += a4.y*w4.x; acc[1][1] += a4.y*w4.y; acc[1][2] += a4.y*w4.z; acc[1][3] += a4.y*w4.w;
      acc[2][0] += a4.z*w4.x; acc[2][1] += a4.z*w4.y; acc[2][2] += a4.z*w4.z; acc[2][3] += a4.z*w4.w;
      acc[3][0] += a4.w*w4.x; acc[3][1] += a4.w*w4.y; acc[3][2] += a4.w*w4.z; acc[3][3] += a4.w*w4.w;
    }
  }
  float b0 = 0.f, b1 = 0.f, b2 = 0.f, b3 = 0.f;
  if (bias) {
    const int n0 = bx * 64 + tx * 4;
    b0 = bias[n0]; b1 = bias[n0 + 1]; b2 = bias[n0 + 2]; b3 = bias[n0 + 3];
  }
#pragma unroll
  for (int i = 0; i < 4; ++i) {
    float4 o = make_float4(acc[i][0] + b0, acc[i][1] + b1, acc[i][2] + b2, acc[i][3] + b3);
    *(float4*)(out + (size_t)(by * 64 + ty * 4 + i) * 512 + bx * 64 + tx * 4) = o;
  }
}

// In-place: Y := mobius_add(expmap0(Y), bias_ball). One block per row.
__global__ __launch_bounds__(256) void hyp_epilogue_kernel(float* __restrict__ Y,
                                                           const float* __restrict__ bb) {
  const int row = blockIdx.x;
  const int t = threadIdx.x;
  float2 y = ((float2*)(Y + (size_t)row * 512))[t];
  float2 w = ((const float2*)bb)[t];
  __shared__ float red[8];
  float sn = wave_sum64(y.x*y.x + y.y*y.y);
  float sd = wave_sum64(y.x*w.x + y.y*w.y);
  if ((t & 63) == 0) { red[t >> 6] = sn; red[4 + (t >> 6)] = sd; }
  __syncthreads();
  float n2 = red[0] + red[1] + red[2] + red[3];
  float dt = red[4] + red[5] + red[6] + red[7];
  float y2 = bb[512];
  // expmap0
  float n  = sqrtf(n2);
  float nm = fmaxf(n, EPSF);
  float tt = fminf(nm, 15.f);
  float f  = tanhf(tt) / nm;
  float on = f * nm;
  if (on > CLAMPF) f *= CLAMPF / on;
  // mobius_add scalars
  float x2 = f * f * n2;
  float xy = f * dt;
  float A  = 1.f + 2.f*xy + y2;
  float Bc = 1.f - x2;
  float den = fmaxf(1.f + 2.f*xy + x2*y2, EPSF);
  float num2 = A*A*x2 + Bc*Bc*y2 + 2.f*A*Bc*xy;
  float nn = sqrtf(fmaxf(num2, 0.f)) / den;
  float nnm = fmaxf(nn, EPSF);
  float s2 = (nnm > CLAMPF) ? (CLAMPF / nnm) : 1.f;
  float g = s2 / den;
  float2 o;
  o.x = g * (A * f * y.x + Bc * w.x);
  o.y = g * (A * f * y.y + Bc * w.y);
  ((float2*)(Y + (size_t)row * 512))[t] = o;
}

// Flash-style hyperbolic attention. Grid (T/32, h, B), block 256.
// Q,K,V,O all stored [B*T][512] with head hd occupying cols hd*64..+64.
__global__ __launch_bounds__(256) void attn_kernel(const float* __restrict__ Q,
                                                   const float* __restrict__ K,
                                                   const float* __restrict__ V,
                                                   float* __restrict__ O) {
  __shared__ float Qs[32][68];
  __shared__ float Ks[64][68];
  __shared__ float Vs[64][68];
  __shared__ float Ps[32][68];
  __shared__ float q2s[32];
  __shared__ float k2s[64];
  const int t  = threadIdx.x;
  const int qt = blockIdx.x, hd = blockIdx.y, b = blockIdx.z;
  const size_t cbase = (size_t)b * 1024 * 512 + (size_t)hd * 64;

  // stage Q tile: 32 rows x 16 float4 = 512 float4s, 2 iters x 256 threads
  {
    int p = t;
#pragma unroll
    for (int it = 0; it < 2; ++it, p += 256) {
      int r = p >> 4, j4 = p & 15;
      *(float4*)&Qs[r][j4 * 4] =
          *(const float4*)(Q + cbase + (size_t)(qt * 32 + r) * 512 + j4 * 4);
    }
  }
  __syncthreads();
  if (t < 32) {
    float s = 0.f;
#pragma unroll
    for (int j4 = 0; j4 < 16; ++j4) {
      float4 v = *(const float4*)&Qs[t][j4 * 4];
      s += v.x*v.x + v.y*v.y + v.z*v.z + v.w*v.w;
    }
    q2s[t] = s;
  }

  const int qp = t >> 4, kgp = t & 15;
  const int q0 = qp * 2, q1 = q0 + 1;
  float4 acc0 = {0,0,0,0}, acc1 = {0,0,0,0};
  float ls0 = 0.f, ls1 = 0.f;

  for (int kt = 0; kt < 16; ++kt) {
    __syncthreads();  // prior tile fully consumed (also publishes q2s on kt=0)
    // stage K/V tile: 64 rows x 16 float4 = 1024 float4s each, 4 iters x 256 threads
    {
      int p = t;
#pragma unroll
      for (int it = 0; it < 4; ++it, p += 256) {
        int r = p >> 4, j4 = p & 15;
        size_t off = cbase + (size_t)(kt * 64 + r) * 512 + j4 * 4;
        *(float4*)&Ks[r][j4 * 4] = *(const float4*)(K + off);
        *(float4*)&Vs[r][j4 * 4] = *(const float4*)(V + off);
      }
    }
    __syncthreads();
    if (t < 64) {
      float s = 0.f;
#pragma unroll
      for (int j4 = 0; j4 < 16; ++j4) {
        float4 v = *(const float4*)&Ks[t][j4 * 4];
        s += v.x*v.x + v.y*v.y + v.z*v.z + v.w*v.w;
      }
      k2s[t] = s;
    }
    __syncthreads();
    // scores: this thread handles queries {q0,q1} x keys {u*16+kgp}
    float dot0[4] = {0,0,0,0}, dot1[4] = {0,0,0,0};
#pragma unroll
    for (int j4 = 0; j4 < 16; ++j4) {
      float4 qa = *(const float4*)&Qs[q0][j4 * 4];
      float4 qb = *(const float4*)&Qs[q1][j4 * 4];
#pragma unroll
      for (int u = 0; u < 4; ++u) {
        float4 kv = *(const float4*)&Ks[u * 16 + kgp][j4 * 4];
        dot0[u] += qa.x*kv.x + qa.y*kv.y + qa.z*kv.z + qa.w*kv.w;
        dot1[u] += qb.x*kv.x + qb.y*kv.y + qb.z*kv.z + qb.w*kv.w;
      }
    }
    float q2a = q2s[q0], q2b = q2s[q1];
#pragma unroll
    for (int u = 0; u < 4; ++u) {
      int s = u * 16 + kgp;
      float k2 = k2s[s];
      float p0 = expf(hyp_score(q2a, k2, dot0[u]));
      float p1 = expf(hyp_score(q2b, k2, dot1[u]));
      Ps[q0][s] = p0; ls0 += p0;
      Ps[q1][s] = p1; ls1 += p1;
    }
    __syncthreads();
    // PV: this thread owns dims kgp*4..+4 for queries q0,q1
#pragma unroll 8
    for (int s = 0; s < 64; ++s) {
      float pv0 = Ps[q0][s], pv1 = Ps[q1][s];
      float4 vv = *(const float4*)&Vs[s][kgp * 4];
      acc0.x += pv0*vv.x; acc0.y += pv0*vv.y; acc0.z += pv0*vv.z; acc0.w += pv0*vv.w;
      acc1.x += pv1*vv.x; acc1.y += pv1*vv.y; acc1.z += pv1*vv.z; acc1.w += pv1*vv.w;
    }
  }
  // softmax denominators: reduce over the 16 kgp lanes (same qp group, within-wave)
#pragma unroll
  for (int m = 1; m < 16; m <<= 1) {
    ls0 += __shfl_xor(ls0, m, 64);
    ls1 += __shfl_xor(ls1, m, 64);
  }
  float i0 = 1.f / ls0, i1 = 1.f / ls1;
  size_t o0 = cbase + (size_t)(qt * 32 + q0) * 512 + kgp * 4;
  size_t o1 = cbase + (size_t)(qt * 32 + q1) * 512 + kgp * 4;
  *(float4*)(O + o0) = make_float4(acc0.x*i0, acc0.y*i0, acc0.z*i0, acc0.w*i0);
  *(float4*)(O + o1) = make_float4(acc1.x*i1, acc1.y*i1, acc1.z*i1, acc1.w*i1);
}

// ---------------- launch ----------------
extern "C" void kernel_launch(void* const* d_in, const int* in_sizes, int n_in,
                              void* d_out, int out_size, void* d_ws, size_t ws_size,
                              hipStream_t stream) {
  const float* x  = (const float*)d_in[0];
  const float* Wq = (const float*)d_in[1];
  const float* bq = (const float*)d_in[2];
  const float* Wk = (const float*)d_in[3];
  const float* bk = (const float*)d_in[4];
  const float* Wv = (const float*)d_in[5];
  const float* bv = (const float*)d_in[6];
  const float* Wo = (const float*)d_in[7];
  const float* bo = (const float*)d_in[8];
  float* out = (float*)d_out;
  float* ws  = (float*)d_ws;

  const size_t NEL = 4096ull * 512ull;  // 2,097,152
  float* xe = ws;                 // x_eucl; reused as attention output O
  float* Qb = ws + NEL;
  float* Kb = ws + 2 * NEL;
  float* Vb = ws + 3 * NEL;
  float* bb = ws + 4 * NEL;       // 2 x 520 floats

  hipLaunchKernelGGL(bias_ball_kernel, dim3(2), dim3(256), 0, stream, bq, bk, bb);
  hipLaunchKernelGGL(logmap_kernel, dim3(4096), dim3(256), 0, stream, x, xe);

  dim3 gg(8, 64);  // (N/64, M/64)
  hipLaunchKernelGGL(gemm_nt_kernel, gg, dim3(256), 0, stream, xe, Wq, (const float*)nullptr, Qb);
  hipLaunchKernelGGL(gemm_nt_kernel, gg, dim3(256), 0, stream, xe, Wk, (const float*)nullptr, Kb);
  hipLaunchKernelGGL(gemm_nt_kernel, gg, dim3(256), 0, stream, xe, Wv, bv, Vb);

  hipLaunchKernelGGL(hyp_epilogue_kernel, dim3(4096), dim3(256), 0, stream, Qb, bb);
  hipLaunchKernelGGL(hyp_epilogue_kernel, dim3(4096), dim3(256), 0, stream, Kb, bb + 520);

  hipLaunchKernelGGL(attn_kernel, dim3(32, 8, 4), dim3(256), 0, stream, Qb, Kb, Vb, xe);

  hipLaunchKernelGGL(gemm_nt_kernel, gg, dim3(256), 0, stream, xe, Wo, bo, out);
}

// Round 3
// 157.513 us; speedup vs baseline: 2.5490x; 2.5490x over previous
//
#include <hip/hip_runtime.h>
#include <math.h>

#define EPSF   1e-8f
#define CLAMPF 0.99999f   // 1 - 1e-5 (f32)

typedef __attribute__((ext_vector_type(8))) short bf16x8;
typedef __attribute__((ext_vector_type(4))) float f32x4;
#define MFMA16(a,b,c) __builtin_amdgcn_mfma_f32_16x16x32_bf16(a,b,c,0,0,0)

__device__ __forceinline__ short f2bf(float f) {
  union { float f; unsigned u; } v; v.f = f;
  unsigned r = v.u + 0x7fffu + ((v.u >> 16) & 1u);
  return (short)(r >> 16);
}

__device__ __forceinline__ float wave_sum64(float v) {
  v += __shfl_xor(v, 1, 64);
  v += __shfl_xor(v, 2, 64);
  v += __shfl_xor(v, 4, 64);
  v += __shfl_xor(v, 8, 64);
  v += __shfl_xor(v, 16, 64);
  v += __shfl_xor(v, 32, 64);
  return v;
}

// ---------------- small fp32 kernels ----------------

// bias_ball = expmap0(b) for bq (block 0) and bk (block 1); 520 floats each.
__global__ __launch_bounds__(256) void bias_ball_kernel(const float* __restrict__ bq,
                                                        const float* __restrict__ bk,
                                                        float* __restrict__ bb) {
  const int which = blockIdx.x;
  const float* b = which ? bk : bq;
  float* o = bb + (size_t)which * 520;
  const int t = threadIdx.x;
  float2 v = ((const float2*)b)[t];
  __shared__ float red[4];
  float s = wave_sum64(v.x*v.x + v.y*v.y);
  if ((t & 63) == 0) red[t >> 6] = s;
  __syncthreads();
  float n2 = red[0] + red[1] + red[2] + red[3];
  float n  = sqrtf(n2);
  float nm = fmaxf(n, EPSF);
  float tt = fminf(nm, 15.f);
  float f  = tanhf(tt) / nm;
  float on = f * nm;
  if (on > CLAMPF) f *= CLAMPF / on;
  ((float2*)o)[t] = make_float2(f * v.x, f * v.y);
  if (t == 0) o[512] = f * f * n2;
}

// xe = logmap0(x). One block per row.
__global__ __launch_bounds__(256) void logmap_kernel(const float* __restrict__ x,
                                                     float* __restrict__ xe) {
  const int row = blockIdx.x;
  const int t = threadIdx.x;
  float2 v = ((const float2*)(x + (size_t)row * 512))[t];
  __shared__ float red[4];
  float s = wave_sum64(v.x*v.x + v.y*v.y);
  if ((t & 63) == 0) red[t >> 6] = s;
  __syncthreads();
  float n2 = red[0] + red[1] + red[2] + red[3];
  float n  = sqrtf(n2);
  float nm = fmaxf(n, EPSF);
  float a  = fminf(nm, 1.0f);
  float at = 0.5f * logf((1.f + a) / (1.f - a));
  float sc = at / nm;
  ((float2*)(xe + (size_t)row * 512))[t] = make_float2(v.x * sc, v.y * sc);
}

// ---------------- bf16 MFMA GEMM: out[m][n] = sum_k A[m][k] W[n][k] (+bias[n]) ----------------
// M=4096 (grid.y*64), N=512 (grid.x*64), K=512. A,W fp32; cast to bf16 on stage; fp32 accum.
__global__ __launch_bounds__(256) void gemm_mfma(const float* __restrict__ A,
                                                 const float* __restrict__ W,
                                                 const float* __restrict__ bias,
                                                 float* __restrict__ out) {
  __shared__ __align__(16) short As[64][72];
  __shared__ __align__(16) short Ws[64][72];
  const int t = threadIdx.x;
  const int bx = blockIdx.x, by = blockIdx.y;
  const int wave = t >> 6, lane = t & 63, lg = lane >> 4, lr = lane & 15;
  const int mh = wave & 1, nh = wave >> 1;
  f32x4 z = {0.f, 0.f, 0.f, 0.f};
  f32x4 acc00 = z, acc01 = z, acc10 = z, acc11 = z;
  const int srow = t >> 2, scol = (t & 3) * 16;
  const float* Ab = A + (size_t)(by * 64 + srow) * 512 + scol;
  const float* Wb = W + (size_t)(bx * 64 + srow) * 512 + scol;

  for (int kt = 0; kt < 512; kt += 64) {
    __syncthreads();
    float4 a0 = *(const float4*)(Ab + kt);
    float4 a1 = *(const float4*)(Ab + kt + 4);
    float4 a2 = *(const float4*)(Ab + kt + 8);
    float4 a3 = *(const float4*)(Ab + kt + 12);
    float4 w0 = *(const float4*)(Wb + kt);
    float4 w1 = *(const float4*)(Wb + kt + 4);
    float4 w2 = *(const float4*)(Wb + kt + 8);
    float4 w3 = *(const float4*)(Wb + kt + 12);
    union { int4 v; short s[8]; } u;
    u.s[0]=f2bf(a0.x); u.s[1]=f2bf(a0.y); u.s[2]=f2bf(a0.z); u.s[3]=f2bf(a0.w);
    u.s[4]=f2bf(a1.x); u.s[5]=f2bf(a1.y); u.s[6]=f2bf(a1.z); u.s[7]=f2bf(a1.w);
    *(int4*)&As[srow][scol] = u.v;
    u.s[0]=f2bf(a2.x); u.s[1]=f2bf(a2.y); u.s[2]=f2bf(a2.z); u.s[3]=f2bf(a2.w);
    u.s[4]=f2bf(a3.x); u.s[5]=f2bf(a3.y); u.s[6]=f2bf(a3.z); u.s[7]=f2bf(a3.w);
    *(int4*)&As[srow][scol + 8] = u.v;
    u.s[0]=f2bf(w0.x); u.s[1]=f2bf(w0.y); u.s[2]=f2bf(w0.z); u.s[3]=f2bf(w0.w);
    u.s[4]=f2bf(w1.x); u.s[5]=f2bf(w1.y); u.s[6]=f2bf(w1.z); u.s[7]=f2bf(w1.w);
    *(int4*)&Ws[srow][scol] = u.v;
    u.s[0]=f2bf(w2.x); u.s[1]=f2bf(w2.y); u.s[2]=f2bf(w2.z); u.s[3]=f2bf(w2.w);
    u.s[4]=f2bf(w3.x); u.s[5]=f2bf(w3.y); u.s[6]=f2bf(w3.z); u.s[7]=f2bf(w3.w);
    *(int4*)&Ws[srow][scol + 8] = u.v;
    __syncthreads();
#pragma unroll
    for (int kk = 0; kk < 2; ++kk) {
      bf16x8 af0 = *(const bf16x8*)&As[mh*32 + lr     ][kk*32 + lg*8];
      bf16x8 af1 = *(const bf16x8*)&As[mh*32 + 16 + lr][kk*32 + lg*8];
      bf16x8 bf0 = *(const bf16x8*)&Ws[nh*32 + lr     ][kk*32 + lg*8];
      bf16x8 bf1 = *(const bf16x8*)&Ws[nh*32 + 16 + lr][kk*32 + lg*8];
      acc00 = MFMA16(af0, bf0, acc00);
      acc01 = MFMA16(af0, bf1, acc01);
      acc10 = MFMA16(af1, bf0, acc10);
      acc11 = MFMA16(af1, bf1, acc11);
    }
  }
  float b0 = 0.f, b1 = 0.f;
  if (bias) { b0 = bias[bx*64 + nh*32 + lr]; b1 = bias[bx*64 + nh*32 + 16 + lr]; }
#pragma unroll
  for (int r = 0; r < 4; ++r) {
    size_t row0 = (size_t)(by*64 + mh*32 + lg*4 + r);
    size_t row1 = row0 + 16;
    out[row0*512 + bx*64 + nh*32 + lr]      = acc00[r] + b0;
    out[row0*512 + bx*64 + nh*32 + 16 + lr] = acc01[r] + b1;
    out[row1*512 + bx*64 + nh*32 + lr]      = acc10[r] + b0;
    out[row1*512 + bx*64 + nh*32 + 16 + lr] = acc11[r] + b1;
  }
}

// ---------------- hyperbolic epilogue: Ybf = bf16(mobius_add(expmap0(Y), bias_ball)), y2h = per-head norms ----------------
__global__ __launch_bounds__(256) void hyp_epilogue_v2(const float* __restrict__ Y,
                                                       const float* __restrict__ bb,
                                                       short* __restrict__ Ybf,
                                                       float* __restrict__ y2h) {
  const int row = blockIdx.x;
  const int t = threadIdx.x;
  float2 y = ((const float2*)(Y + (size_t)row * 512))[t];
  float2 w = ((const float2*)bb)[t];
  __shared__ float red[8];
  float sn = wave_sum64(y.x*y.x + y.y*y.y);
  float sd = wave_sum64(y.x*w.x + y.y*w.y);
  if ((t & 63) == 0) { red[t >> 6] = sn; red[4 + (t >> 6)] = sd; }
  __syncthreads();
  float n2 = red[0] + red[1] + red[2] + red[3];
  float dt = red[4] + red[5] + red[6] + red[7];
  float y2 = bb[512];
  float n  = sqrtf(n2);
  float nm = fmaxf(n, EPSF);
  float tt = fminf(nm, 15.f);
  float f  = tanhf(tt) / nm;
  float on = f * nm;
  if (on > CLAMPF) f *= CLAMPF / on;
  float x2 = f * f * n2;
  float xy = f * dt;
  float A  = 1.f + 2.f*xy + y2;
  float Bc = 1.f - x2;
  float den = fmaxf(1.f + 2.f*xy + x2*y2, EPSF);
  float num2 = A*A*x2 + Bc*Bc*y2 + 2.f*A*Bc*xy;
  float nn = sqrtf(fmaxf(num2, 0.f)) / den;
  float nnm = fmaxf(nn, EPSF);
  float s2 = (nnm > CLAMPF) ? (CLAMPF / nnm) : 1.f;
  float g = s2 / den;
  float ox = g * (A * f * y.x + Bc * w.x);
  float oy = g * (A * f * y.y + Bc * w.y);
  // bf16 write (elements 2t, 2t+1)
  unsigned hb0 = (unsigned short)f2bf(ox);
  unsigned hb1 = (unsigned short)f2bf(oy);
  ((unsigned*)(Ybf + (size_t)row * 512))[t] = (hb1 << 16) | hb0;
  // per-head norm: head = t>>5, 32 threads per head
  float hs = ox*ox + oy*oy;
  hs += __shfl_xor(hs, 1, 64);
  hs += __shfl_xor(hs, 2, 64);
  hs += __shfl_xor(hs, 4, 64);
  hs += __shfl_xor(hs, 8, 64);
  hs += __shfl_xor(hs, 16, 64);
  if ((t & 31) == 0) y2h[(size_t)row * 8 + (t >> 5)] = hs;
}

// ---------------- V transpose: Vb fp32 [4096][512] -> Vt bf16 [b][h][dv=64][t=1024] ----------------
__global__ __launch_bounds__(256) void vtrans_kernel(const float* __restrict__ Vb,
                                                     short* __restrict__ Vt) {
  __shared__ __align__(16) short Ts[64][72];
  const int t = threadIdx.x;
  const int tt0 = blockIdx.x * 64, hd = blockIdx.y, b = blockIdx.z;
  const int r = t >> 2, c0 = (t & 3) * 16;
  const float* src = Vb + (size_t)(b*1024 + tt0 + r) * 512 + hd*64 + c0;
  float4 v0 = *(const float4*)(src);
  float4 v1 = *(const float4*)(src + 4);
  float4 v2 = *(const float4*)(src + 8);
  float4 v3 = *(const float4*)(src + 12);
  Ts[c0+ 0][r]=f2bf(v0.x); Ts[c0+ 1][r]=f2bf(v0.y); Ts[c0+ 2][r]=f2bf(v0.z); Ts[c0+ 3][r]=f2bf(v0.w);
  Ts[c0+ 4][r]=f2bf(v1.x); Ts[c0+ 5][r]=f2bf(v1.y); Ts[c0+ 6][r]=f2bf(v1.z); Ts[c0+ 7][r]=f2bf(v1.w);
  Ts[c0+ 8][r]=f2bf(v2.x); Ts[c0+ 9][r]=f2bf(v2.y); Ts[c0+10][r]=f2bf(v2.z); Ts[c0+11][r]=f2bf(v2.w);
  Ts[c0+12][r]=f2bf(v3.x); Ts[c0+13][r]=f2bf(v3.y); Ts[c0+14][r]=f2bf(v3.z); Ts[c0+15][r]=f2bf(v3.w);
  __syncthreads();
  const int dv = t >> 3, ch = t & 7;
  short* dst0 = Vt + ((size_t)((b*8 + hd)*64 + dv)      )*1024 + tt0 + ch*8;
  short* dst1 = Vt + ((size_t)((b*8 + hd)*64 + dv + 32) )*1024 + tt0 + ch*8;
  *(int4*)dst0 = *(const int4*)&Ts[dv     ][ch*8];
  *(int4*)dst1 = *(const int4*)&Ts[dv + 32][ch*8];
}

// ---------------- MFMA flash attention ----------------
// Grid 1024 (1D, XCD-friendly decode), 256 threads = 4 waves.
// Wave w: QK keys [16w,16w+16), PV dv [16w,16w+16). QBLK=32, KBLK=64.
__global__ __launch_bounds__(256) void attn_mfma(const short* __restrict__ Qbf,
                                                 const short* __restrict__ Kbf,
                                                 const float* __restrict__ q2h,
                                                 const float* __restrict__ k2h,
                                                 const short* __restrict__ Vt,
                                                 float* __restrict__ O) {
  __shared__ __align__(16) short Qs[32][72];
  __shared__ __align__(16) short Ks[64][72];
  __shared__ __align__(16) short Vs[64][72];
  __shared__ __align__(16) short Ps[32][72];
  __shared__ float k2s[64];
  __shared__ float lsl[4][32];

  const int t = threadIdx.x;
  // decode: same (b,hd) lands on one XCD (id&7 = round-robin XCD)
  const int id = blockIdx.x;
  const int qt = id >> 5;
  const int pr = (((id >> 3) & 3) << 3) | (id & 7);
  const int hd = pr & 7, b = pr >> 3;

  const int wave = t >> 6, lane = t & 63, lg = lane >> 4, lr = lane & 15;
  const size_t hbase = (size_t)b * 1024 * 512 + (size_t)hd * 64;
  const size_t vtb = (size_t)(b * 8 + hd) * 64 * 1024;

  const int sr = t >> 3, sc8 = (t & 7) * 8;

  // stage Q (32 rows x 64 bf16)
  *(int4*)&Qs[sr][sc8] = *(const int4*)(Qbf + hbase + (size_t)(qt*32 + sr)*512 + sc8);
  __syncthreads();

  // Q fragments (persist whole kernel)
  bf16x8 qf[2][2];
#pragma unroll
  for (int m = 0; m < 2; ++m)
#pragma unroll
    for (int kk = 0; kk < 2; ++kk)
      qf[m][kk] = *(const bf16x8*)&Qs[m*16 + lr][kk*32 + lg*8];

  // per-lane query scalars
  float q2v[2][4], bc_[2][4], bc2_[2][4];
#pragma unroll
  for (int m = 0; m < 2; ++m)
#pragma unroll
    for (int r = 0; r < 4; ++r) {
      float q2 = q2h[(size_t)(b*1024 + qt*32 + m*16 + lg*4 + r) * 8 + hd];
      q2v[m][r] = q2;
      bc_[m][r] = 1.f - q2;
      bc2_[m][r] = bc_[m][r] * bc_[m][r];
    }

  f32x4 z = {0.f,0.f,0.f,0.f};
  f32x4 accv[2] = {z, z};
  float ls_[2][4] = {{0.f,0.f,0.f,0.f},{0.f,0.f,0.f,0.f}};

  for (int kt = 0; kt < 16; ++kt) {
    __syncthreads();  // (A) prev iter's Ps/Vs/Ks reads complete
    {
      const size_t kr = hbase + (size_t)(kt*64 + sr)*512 + sc8;
      *(int4*)&Ks[sr     ][sc8] = *(const int4*)(Kbf + kr);
      *(int4*)&Ks[sr + 32][sc8] = *(const int4*)(Kbf + kr + (size_t)32*512);
      const size_t vr = vtb + (size_t)sr*1024 + kt*64 + sc8;
      *(int4*)&Vs[sr     ][sc8] = *(const int4*)(Vt + vr);
      *(int4*)&Vs[sr + 32][sc8] = *(const int4*)(Vt + vr + (size_t)32*1024);
      if (t < 64) k2s[t] = k2h[(size_t)(b*1024 + kt*64 + t) * 8 + hd];
    }
    __syncthreads();  // (B) tiles staged

    // QK^T on this wave's 16-key slice
    bf16x8 kf0 = *(const bf16x8*)&Ks[wave*16 + lr][0  + lg*8];
    bf16x8 kf1 = *(const bf16x8*)&Ks[wave*16 + lr][32 + lg*8];
    f32x4 s0 = z, s1 = z;
    s0 = MFMA16(qf[0][0], kf0, s0);
    s0 = MFMA16(qf[0][1], kf1, s0);
    s1 = MFMA16(qf[1][0], kf0, s1);
    s1 = MFMA16(qf[1][1], kf1, s1);

    // scores -> p = u^0.125, u = (den - sqrt(num2)) / (den + sqrt(num2))
    float k2 = k2s[wave*16 + lr];
    float k2p1 = 1.f + k2;
#pragma unroll
    for (int m = 0; m < 2; ++m) {
      f32x4 sv = m ? s1 : s0;
#pragma unroll
      for (int r = 0; r < 4; ++r) {
        float dot = sv[r];
        float w  = -2.f * dot;
        float A  = k2p1 + w;
        float den = fmaf(q2v[m][r], k2, 1.f) + w;
        den = fmaxf(den, EPSF);
        float num2 = A * A * q2v[m][r];
        num2 = fmaf(bc2_[m][r], k2, num2);
        num2 = fmaf(A * bc_[m][r], w, num2);
        num2 = fmaxf(num2, 0.f);
        float sq = sqrtf(num2);
        float u = (den - sq) * __builtin_amdgcn_rcpf(den + sq);
        u = fmaxf(u, 5.000025e-6f);   // n <= 0.99999 clamp
        float p = exp2f(0.125f * log2f(u));
        ls_[m][r] += p;
        Ps[m*16 + lg*4 + r][wave*16 + lr] = f2bf(p);
      }
    }
    __syncthreads();  // (C) P tile complete

    // PV: this wave's dv slice
    bf16x8 vf0 = *(const bf16x8*)&Vs[wave*16 + lr][0  + lg*8];
    bf16x8 vf1 = *(const bf16x8*)&Vs[wave*16 + lr][32 + lg*8];
    bf16x8 pa00 = *(const bf16x8*)&Ps[lr     ][0  + lg*8];
    bf16x8 pa01 = *(const bf16x8*)&Ps[lr     ][32 + lg*8];
    bf16x8 pa10 = *(const bf16x8*)&Ps[16 + lr][0  + lg*8];
    bf16x8 pa11 = *(const bf16x8*)&Ps[16 + lr][32 + lg*8];
    accv[0] = MFMA16(pa00, vf0, accv[0]);
    accv[0] = MFMA16(pa01, vf1, accv[0]);
    accv[1] = MFMA16(pa10, vf0, accv[1]);
    accv[1] = MFMA16(pa11, vf1, accv[1]);
  }

  // softmax denominators: reduce over the 16 lr lanes, then across waves
#pragma unroll
  for (int m = 0; m < 2; ++m)
#pragma unroll
    for (int r = 0; r < 4; ++r) {
      float v = ls_[m][r];
      v += __shfl_xor(v, 1, 64);
      v += __shfl_xor(v, 2, 64);
      v += __shfl_xor(v, 4, 64);
      v += __shfl_xor(v, 8, 64);
      ls_[m][r] = v;
    }
  if (lr == 0) {
#pragma unroll
    for (int m = 0; m < 2; ++m)
#pragma unroll
      for (int r = 0; r < 4; ++r)
        lsl[wave][m*16 + lg*4 + r] = ls_[m][r];
  }
  __syncthreads();

  float* Ob = O + (size_t)b * 1024 * 512;
#pragma unroll
  for (int m = 0; m < 2; ++m)
#pragma unroll
    for (int r = 0; r < 4; ++r) {
      int q = m*16 + lg*4 + r;
      float s = lsl[0][q] + lsl[1][q] + lsl[2][q] + lsl[3][q];
      float inv = 1.f / s;
      Ob[(size_t)(qt*32 + q)*512 + hd*64 + wave*16 + lr] = accv[m][r] * inv;
    }
}

// ---------------- launch ----------------
extern "C" void kernel_launch(void* const* d_in, const int* in_sizes, int n_in,
                              void* d_out, int out_size, void* d_ws, size_t ws_size,
                              hipStream_t stream) {
  const float* x  = (const float*)d_in[0];
  const float* Wq = (const float*)d_in[1];
  const float* bq = (const float*)d_in[2];
  const float* Wk = (const float*)d_in[3];
  const float* bk = (const float*)d_in[4];
  const float* Wv = (const float*)d_in[5];
  const float* bv = (const float*)d_in[6];
  const float* Wo = (const float*)d_in[7];
  const float* bo = (const float*)d_in[8];
  float* out = (float*)d_out;
  float* ws  = (float*)d_ws;

  const size_t NEL = 4096ull * 512ull;  // 2,097,152 floats per [4096][512] fp32 buffer

  // ws regions (32 MB total, same footprint as round 1):
  float* xe = ws;                       // fp32 [0, NEL)
  float* Qb = ws + NEL;                 // fp32
  float* Kb = ws + 2 * NEL;             // fp32
  float* Vb = ws + 3 * NEL;             // fp32
  // bf16 overlays on dead fp32 regions:
  short* Qbf = (short*)ws;                        // 2M bf16 over xe[0, NEL/2)
  short* Kbf = (short*)(ws + NEL / 2);            // 2M bf16 over xe[NEL/2, NEL)
  short* Vt  = (short*)(ws + NEL);                // 2M bf16 over Qb's first half
  float* attn_out = Kb;                           // fp32, overwrites dead Kb
  // tiny scalars live in d_out's tail-overwritten region:
  float* bb  = out;                     // 2 x 520 floats
  float* q2h = out + 2048;              // 4096*8
  float* k2h = out + 2048 + 32768;      // 4096*8

  hipLaunchKernelGGL(bias_ball_kernel, dim3(2), dim3(256), 0, stream, bq, bk, bb);
  hipLaunchKernelGGL(logmap_kernel, dim3(4096), dim3(256), 0, stream, x, xe);

  dim3 gg(8, 64);  // (N/64, M/64)
  hipLaunchKernelGGL(gemm_mfma, gg, dim3(256), 0, stream, xe, Wq, (const float*)nullptr, Qb);
  hipLaunchKernelGGL(gemm_mfma, gg, dim3(256), 0, stream, xe, Wk, (const float*)nullptr, Kb);
  hipLaunchKernelGGL(gemm_mfma, gg, dim3(256), 0, stream, xe, Wv, bv, Vb);

  hipLaunchKernelGGL(hyp_epilogue_v2, dim3(4096), dim3(256), 0, stream, Qb, bb,       Qbf, q2h);
  hipLaunchKernelGGL(hyp_epilogue_v2, dim3(4096), dim3(256), 0, stream, Kb, bb + 520, Kbf, k2h);

  hipLaunchKernelGGL(vtrans_kernel, dim3(16, 8, 4), dim3(256), 0, stream, Vb, Vt);

  hipLaunchKernelGGL(attn_mfma, dim3(1024), dim3(256), 0, stream, Qbf, Kbf, q2h, k2h, Vt, attn_out);

  hipLaunchKernelGGL(gemm_mfma, gg, dim3(256), 0, stream, attn_out, Wo, bo, out);
}

// Round 4
// 94.398 us; speedup vs baseline: 4.2533x; 1.6686x over previous
//
#include <hip/hip_runtime.h>
#include <math.h>

#define EPSF   1e-8f
#define CLAMPF 0.99999f   // 1 - 1e-5 (f32)

typedef __attribute__((ext_vector_type(8))) short bf16x8;
typedef __attribute__((ext_vector_type(4))) float f32x4;
#define MFMA16(a,b,c) __builtin_amdgcn_mfma_f32_16x16x32_bf16(a,b,c,0,0,0)

__device__ __forceinline__ short f2bf(float f) {
  union { float f; unsigned u; } v; v.f = f;
  unsigned r = v.u + 0x7fffu + ((v.u >> 16) & 1u);
  return (short)(r >> 16);
}

// hardware packed f32x2 -> bf16x2 (single VALU instr)
__device__ __forceinline__ unsigned cvt_pk_bf16(float lo, float hi) {
  unsigned r;
  asm("v_cvt_pk_bf16_f32 %0, %1, %2" : "=v"(r) : "v"(lo), "v"(hi));
  return r;
}

__device__ __forceinline__ float wave_sum64(float v) {
  v += __shfl_xor(v, 1, 64);
  v += __shfl_xor(v, 2, 64);
  v += __shfl_xor(v, 4, 64);
  v += __shfl_xor(v, 8, 64);
  v += __shfl_xor(v, 16, 64);
  v += __shfl_xor(v, 32, 64);
  return v;
}

// ---------------- prep: weight fp32->bf16 (by<4) + bias_ball (by==4) ----------------
__global__ __launch_bounds__(256) void prep_kernel(const float* __restrict__ Wq,
                                                   const float* __restrict__ Wk,
                                                   const float* __restrict__ Wv,
                                                   const float* __restrict__ Wo,
                                                   const float* __restrict__ bq,
                                                   const float* __restrict__ bk,
                                                   short* __restrict__ Wqbf,
                                                   short* __restrict__ Wkbf,
                                                   short* __restrict__ Wvbf,
                                                   short* __restrict__ Wobf,
                                                   float* __restrict__ bb) {
  const int by = blockIdx.y;
  const int t = threadIdx.x;
  if (by < 4) {
    const float* src; short* dst;
    switch (by) {
      case 0: src = Wq; dst = Wqbf; break;
      case 1: src = Wk; dst = Wkbf; break;
      case 2: src = Wv; dst = Wvbf; break;
      default: src = Wo; dst = Wobf; break;
    }
    const int idx = blockIdx.x * 2048 + t * 8;
    float4 a = *(const float4*)(src + idx);
    float4 b2 = *(const float4*)(src + idx + 4);
    union { int4 v; unsigned u[4]; } o;
    o.u[0] = cvt_pk_bf16(a.x, a.y);
    o.u[1] = cvt_pk_bf16(a.z, a.w);
    o.u[2] = cvt_pk_bf16(b2.x, b2.y);
    o.u[3] = cvt_pk_bf16(b2.z, b2.w);
    *(int4*)(dst + idx) = o.v;
    return;
  }
  // bias_ball = expmap0(b) for bq (bx 0) and bk (bx 1); 520 floats each
  if (blockIdx.x >= 2) return;
  const int which = blockIdx.x;
  const float* b = which ? bk : bq;
  float* o = bb + (size_t)which * 520;
  float2 v = ((const float2*)b)[t];
  __shared__ float red[4];
  float s = wave_sum64(v.x * v.x + v.y * v.y);
  if ((t & 63) == 0) red[t >> 6] = s;
  __syncthreads();
  float n2 = red[0] + red[1] + red[2] + red[3];
  float n = sqrtf(n2);
  float nm = fmaxf(n, EPSF);
  float tt = fminf(nm, 15.f);
  float f = tanhf(tt) / nm;
  float on = f * nm;
  if (on > CLAMPF) f *= CLAMPF / on;
  ((float2*)o)[t] = make_float2(f * v.x, f * v.y);
  if (t == 0) o[512] = f * f * n2;
}

// ---------------- xe = bf16(logmap0(x)) ----------------
__global__ __launch_bounds__(256) void logmap_kernel(const float* __restrict__ x,
                                                     short* __restrict__ xe) {
  const int row = blockIdx.x;
  const int t = threadIdx.x;
  float2 v = ((const float2*)(x + (size_t)row * 512))[t];
  __shared__ float red[4];
  float s = wave_sum64(v.x * v.x + v.y * v.y);
  if ((t & 63) == 0) red[t >> 6] = s;
  __syncthreads();
  float n2 = red[0] + red[1] + red[2] + red[3];
  float n = sqrtf(n2);
  float nm = fmaxf(n, EPSF);
  float a = fminf(nm, 1.0f);
  float at = 0.5f * logf((1.f + a) / (1.f - a));
  float sc = at / nm;
  ((unsigned*)(xe + (size_t)row * 512))[t] = cvt_pk_bf16(v.x * sc, v.y * sc);
}

// ---------------- bf16 MFMA GEMM core: out[m][n] = sum_k A[m][k] W[n][k] (+bias[n]) ----------------
__device__ __forceinline__ void gemm_core(const short* __restrict__ A,
                                          const short* __restrict__ W,
                                          const float* __restrict__ bias,
                                          float* __restrict__ out,
                                          int bx, int by) {
  __shared__ __align__(16) short As[64][72];
  __shared__ __align__(16) short Ws[64][72];
  const int t = threadIdx.x;
  const int wave = t >> 6, lane = t & 63, lg = lane >> 4, lr = lane & 15;
  const int mh = wave & 1, nh = wave >> 1;
  f32x4 z = {0.f, 0.f, 0.f, 0.f};
  f32x4 acc00 = z, acc01 = z, acc10 = z, acc11 = z;
  const int srow = t >> 2, sc = (t & 3) * 16;
  const short* Ab = A + (size_t)(by * 64 + srow) * 512 + sc;
  const short* Wb = W + (size_t)(bx * 64 + srow) * 512 + sc;

  for (int kt = 0; kt < 512; kt += 64) {
    __syncthreads();
    int4 a0 = *(const int4*)(Ab + kt);
    int4 a1 = *(const int4*)(Ab + kt + 8);
    int4 w0 = *(const int4*)(Wb + kt);
    int4 w1 = *(const int4*)(Wb + kt + 8);
    *(int4*)&As[srow][sc] = a0;
    *(int4*)&As[srow][sc + 8] = a1;
    *(int4*)&Ws[srow][sc] = w0;
    *(int4*)&Ws[srow][sc + 8] = w1;
    __syncthreads();
#pragma unroll
    for (int kk = 0; kk < 2; ++kk) {
      bf16x8 af0 = *(const bf16x8*)&As[mh * 32 + lr][kk * 32 + lg * 8];
      bf16x8 af1 = *(const bf16x8*)&As[mh * 32 + 16 + lr][kk * 32 + lg * 8];
      bf16x8 bf0 = *(const bf16x8*)&Ws[nh * 32 + lr][kk * 32 + lg * 8];
      bf16x8 bf1 = *(const bf16x8*)&Ws[nh * 32 + 16 + lr][kk * 32 + lg * 8];
      acc00 = MFMA16(af0, bf0, acc00);
      acc01 = MFMA16(af0, bf1, acc01);
      acc10 = MFMA16(af1, bf0, acc10);
      acc11 = MFMA16(af1, bf1, acc11);
    }
  }
  float b0 = 0.f, b1 = 0.f;
  if (bias) { b0 = bias[bx * 64 + nh * 32 + lr]; b1 = bias[bx * 64 + nh * 32 + 16 + lr]; }
#pragma unroll
  for (int r = 0; r < 4; ++r) {
    size_t row0 = (size_t)(by * 64 + mh * 32 + lg * 4 + r);
    size_t row1 = row0 + 16;
    out[row0 * 512 + bx * 64 + nh * 32 + lr] = acc00[r] + b0;
    out[row0 * 512 + bx * 64 + nh * 32 + 16 + lr] = acc01[r] + b1;
    out[row1 * 512 + bx * 64 + nh * 32 + lr] = acc10[r] + b0;
    out[row1 * 512 + bx * 64 + nh * 32 + 16 + lr] = acc11[r] + b1;
  }
}

// batched QKV GEMM (grid.z selects)
__global__ __launch_bounds__(256) void gemm_qkv(const short* __restrict__ A,
                                                const short* __restrict__ Wq,
                                                const short* __restrict__ Wk,
                                                const short* __restrict__ Wv,
                                                const float* __restrict__ bv,
                                                float* __restrict__ Qo,
                                                float* __restrict__ Ko,
                                                float* __restrict__ Vo) {
  const short* W;
  const float* bias = nullptr;
  float* out;
  switch (blockIdx.z) {
    case 0: W = Wq; out = Qo; break;
    case 1: W = Wk; out = Ko; break;
    default: W = Wv; out = Vo; bias = bv; break;
  }
  gemm_core(A, W, bias, out, blockIdx.x, blockIdx.y);
}

__global__ __launch_bounds__(256) void gemm_bf(const short* __restrict__ A,
                                               const short* __restrict__ W,
                                               const float* __restrict__ bias,
                                               float* __restrict__ out) {
  gemm_core(A, W, bias, out, blockIdx.x, blockIdx.y);
}

// ---------------- hyperbolic epilogue (batched Q/K via grid.y) ----------------
// Ybf = bf16(mobius_add(expmap0(Y), bias_ball)); y2h[h][4096] per-head norms
__global__ __launch_bounds__(256) void hyp_epilogue_v3(const float* __restrict__ Qb,
                                                       const float* __restrict__ Kb,
                                                       const float* __restrict__ bbase,
                                                       short* __restrict__ Qbf,
                                                       short* __restrict__ Kbf,
                                                       float* __restrict__ q2h,
                                                       float* __restrict__ k2h) {
  const int row = blockIdx.x;
  const int which = blockIdx.y;
  const float* Y = which ? Kb : Qb;
  const float* bb = bbase + (size_t)which * 520;
  short* Ybf = which ? Kbf : Qbf;
  float* y2h = which ? k2h : q2h;
  const int t = threadIdx.x;
  float2 y = ((const float2*)(Y + (size_t)row * 512))[t];
  float2 w = ((const float2*)bb)[t];
  __shared__ float red[8];
  float sn = wave_sum64(y.x * y.x + y.y * y.y);
  float sd = wave_sum64(y.x * w.x + y.y * w.y);
  if ((t & 63) == 0) { red[t >> 6] = sn; red[4 + (t >> 6)] = sd; }
  __syncthreads();
  float n2 = red[0] + red[1] + red[2] + red[3];
  float dt = red[4] + red[5] + red[6] + red[7];
  float y2 = bb[512];
  float n = sqrtf(n2);
  float nm = fmaxf(n, EPSF);
  float tt = fminf(nm, 15.f);
  float f = tanhf(tt) / nm;
  float on = f * nm;
  if (on > CLAMPF) f *= CLAMPF / on;
  float x2 = f * f * n2;
  float xy = f * dt;
  float A = 1.f + 2.f * xy + y2;
  float Bc = 1.f - x2;
  float den = fmaxf(1.f + 2.f * xy + x2 * y2, EPSF);
  float num2 = A * A * x2 + Bc * Bc * y2 + 2.f * A * Bc * xy;
  float nn = sqrtf(fmaxf(num2, 0.f)) / den;
  float nnm = fmaxf(nn, EPSF);
  float s2 = (nnm > CLAMPF) ? (CLAMPF / nnm) : 1.f;
  float g = s2 / den;
  float ox = g * (A * f * y.x + Bc * w.x);
  float oy = g * (A * f * y.y + Bc * w.y);
  ((unsigned*)(Ybf + (size_t)row * 512))[t] = cvt_pk_bf16(ox, oy);
  // per-head norm in fp32 (head = t>>5)
  float hs = ox * ox + oy * oy;
  hs += __shfl_xor(hs, 1, 64);
  hs += __shfl_xor(hs, 2, 64);
  hs += __shfl_xor(hs, 4, 64);
  hs += __shfl_xor(hs, 8, 64);
  hs += __shfl_xor(hs, 16, 64);
  if ((t & 31) == 0) y2h[(size_t)(t >> 5) * 4096 + row] = hs;
}

// ---------------- V transpose: Vb fp32 [4096][512] -> Vt bf16 [b][h][dv=64][t=1024] ----------------
__global__ __launch_bounds__(256) void vtrans_kernel(const float* __restrict__ Vb,
                                                     short* __restrict__ Vt) {
  __shared__ __align__(16) short Ts[64][72];
  const int t = threadIdx.x;
  const int tt0 = blockIdx.x * 64, hd = blockIdx.y, b = blockIdx.z;
  const int r = t >> 2, c0 = (t & 3) * 16;
  const float* src = Vb + (size_t)(b * 1024 + tt0 + r) * 512 + hd * 64 + c0;
  float4 v0 = *(const float4*)(src);
  float4 v1 = *(const float4*)(src + 4);
  float4 v2 = *(const float4*)(src + 8);
  float4 v3 = *(const float4*)(src + 12);
  Ts[c0 + 0][r] = f2bf(v0.x); Ts[c0 + 1][r] = f2bf(v0.y); Ts[c0 + 2][r] = f2bf(v0.z); Ts[c0 + 3][r] = f2bf(v0.w);
  Ts[c0 + 4][r] = f2bf(v1.x); Ts[c0 + 5][r] = f2bf(v1.y); Ts[c0 + 6][r] = f2bf(v1.z); Ts[c0 + 7][r] = f2bf(v1.w);
  Ts[c0 + 8][r] = f2bf(v2.x); Ts[c0 + 9][r] = f2bf(v2.y); Ts[c0 + 10][r] = f2bf(v2.z); Ts[c0 + 11][r] = f2bf(v2.w);
  Ts[c0 + 12][r] = f2bf(v3.x); Ts[c0 + 13][r] = f2bf(v3.y); Ts[c0 + 14][r] = f2bf(v3.z); Ts[c0 + 15][r] = f2bf(v3.w);
  __syncthreads();
  const int dv = t >> 3, ch = t & 7;
  short* dst0 = Vt + ((size_t)((b * 8 + hd) * 64 + dv)) * 1024 + tt0 + ch * 8;
  short* dst1 = Vt + ((size_t)((b * 8 + hd) * 64 + dv + 32)) * 1024 + tt0 + ch * 8;
  *(int4*)dst0 = *(const int4*)&Ts[dv][ch * 8];
  *(int4*)dst1 = *(const int4*)&Ts[dv + 32][ch * 8];
}

// ---------------- MFMA flash attention ----------------
// Grid 1024 (1D, XCD-friendly decode), 256 threads = 4 waves.
// Wave w: QK keys [16w,16w+16), PV dv [16w,16w+16). QBLK=32, KBLK=64. Output bf16.
__global__ __launch_bounds__(256) void attn_mfma(const short* __restrict__ Qbf,
                                                 const short* __restrict__ Kbf,
                                                 const float* __restrict__ q2h,
                                                 const float* __restrict__ k2h,
                                                 const short* __restrict__ Vt,
                                                 short* __restrict__ Obf) {
  __shared__ __align__(16) short Qs[32][72];
  __shared__ __align__(16) short Ks[64][72];
  __shared__ __align__(16) short Vs[64][72];
  __shared__ __align__(16) short Ps[32][72];
  __shared__ float k2s[64];
  __shared__ float lsl[4][32];

  const int t = threadIdx.x;
  const int id = blockIdx.x;
  const int qt = id >> 5;
  const int pr = (((id >> 3) & 3) << 3) | (id & 7);
  const int hd = pr & 7, b = pr >> 3;

  const int wave = t >> 6, lane = t & 63, lg = lane >> 4, lr = lane & 15;
  const size_t hbase = (size_t)b * 1024 * 512 + (size_t)hd * 64;
  const size_t vtb = (size_t)(b * 8 + hd) * 64 * 1024;
  const int sr = t >> 3, sc8 = (t & 7) * 8;

  // stage Q (32 rows x 64 bf16)
  *(int4*)&Qs[sr][sc8] = *(const int4*)(Qbf + hbase + (size_t)(qt * 32 + sr) * 512 + sc8);
  __syncthreads();

  bf16x8 qf[2][2];
#pragma unroll
  for (int m = 0; m < 2; ++m)
#pragma unroll
    for (int kk = 0; kk < 2; ++kk)
      qf[m][kk] = *(const bf16x8*)&Qs[m * 16 + lr][kk * 32 + lg * 8];

  // per-lane query scalars
  float q2v[2][4], bc_[2][4], bc2_[2][4];
#pragma unroll
  for (int m = 0; m < 2; ++m)
#pragma unroll
    for (int r = 0; r < 4; ++r) {
      float q2 = q2h[(size_t)hd * 4096 + b * 1024 + qt * 32 + m * 16 + lg * 4 + r];
      q2v[m][r] = q2;
      bc_[m][r] = 1.f - q2;
      bc2_[m][r] = bc_[m][r] * bc_[m][r];
    }

  f32x4 z = {0.f, 0.f, 0.f, 0.f};
  f32x4 accT0 = z, accT1 = z;   // O^T fragments: cols q=lr (accT0) and q=16+lr (accT1)
  float ls_[2][4] = {{0.f, 0.f, 0.f, 0.f}, {0.f, 0.f, 0.f, 0.f}};

  const short* kp = Kbf + hbase + (size_t)sr * 512 + sc8;
  const short* vp = Vt + vtb + (size_t)sr * 1024 + sc8;
  const float* k2p = k2h + (size_t)hd * 4096 + b * 1024 + t;

  for (int kt = 0; kt < 16; ++kt) {
    __syncthreads();  // (A) prior tile fully consumed
    *(int4*)&Ks[sr][sc8] = *(const int4*)kp;
    *(int4*)&Ks[sr + 32][sc8] = *(const int4*)(kp + 32 * 512);
    *(int4*)&Vs[sr][sc8] = *(const int4*)vp;
    *(int4*)&Vs[sr + 32][sc8] = *(const int4*)(vp + 32 * 1024);
    if (t < 64) k2s[t] = *k2p;
    kp += 64 * 512; vp += 64; k2p += 64;
    __syncthreads();  // (B) tiles staged

    // QK^T on this wave's 16-key slice
    bf16x8 kf0 = *(const bf16x8*)&Ks[wave * 16 + lr][0 + lg * 8];
    bf16x8 kf1 = *(const bf16x8*)&Ks[wave * 16 + lr][32 + lg * 8];
    f32x4 s0 = z, s1 = z;
    s0 = MFMA16(qf[0][0], kf0, s0);
    s0 = MFMA16(qf[0][1], kf1, s0);
    s1 = MFMA16(qf[1][0], kf0, s1);
    s1 = MFMA16(qf[1][1], kf1, s1);

    float k2 = k2s[wave * 16 + lr];
    float k2p1 = 1.f + k2;
#pragma unroll
    for (int m = 0; m < 2; ++m) {
      f32x4 sv = m ? s1 : s0;
#pragma unroll
      for (int r = 0; r < 4; ++r) {
        float q2 = q2v[m][r];
        float w = -2.f * sv[r];
        float A = k2p1 + w;
        float den = fmaxf(fmaf(q2, k2, 1.f) + w, EPSF);
        float num2 = fmaf(A * bc_[m][r], w, fmaf(A * A, q2, bc2_[m][r] * k2));
        num2 = fmaxf(num2, 0.f);
        float sq = __builtin_amdgcn_sqrtf(num2);
        float u = (den - sq) * __builtin_amdgcn_rcpf(den + sq);
        u = fmaxf(u, 5.000025e-6f);   // n <= 0.99999 clamp
        float p = __builtin_amdgcn_exp2f(0.125f * __builtin_amdgcn_logf(u));
        ls_[m][r] += p;
        unsigned pk = cvt_pk_bf16(p, p);
        Ps[m * 16 + lg * 4 + r][wave * 16 + lr] = (short)(pk & 0xffff);
      }
    }
    __syncthreads();  // (C) P tile complete

    // PV swapped: accT = MFMA(V^T-frag, P-frag) -> O^T[dv][q]
    bf16x8 vf0 = *(const bf16x8*)&Vs[wave * 16 + lr][0 + lg * 8];
    bf16x8 vf1 = *(const bf16x8*)&Vs[wave * 16 + lr][32 + lg * 8];
    bf16x8 pa00 = *(const bf16x8*)&Ps[lr][0 + lg * 8];
    bf16x8 pa01 = *(const bf16x8*)&Ps[lr][32 + lg * 8];
    bf16x8 pa10 = *(const bf16x8*)&Ps[16 + lr][0 + lg * 8];
    bf16x8 pa11 = *(const bf16x8*)&Ps[16 + lr][32 + lg * 8];
    accT0 = MFMA16(vf0, pa00, accT0);
    accT0 = MFMA16(vf1, pa01, accT0);
    accT1 = MFMA16(vf0, pa10, accT1);
    accT1 = MFMA16(vf1, pa11, accT1);
  }

  // softmax denominators: reduce over the 16 lr lanes (keys), publish per-q totals
#pragma unroll
  for (int m = 0; m < 2; ++m)
#pragma unroll
    for (int r = 0; r < 4; ++r) {
      float v = ls_[m][r];
      v += __shfl_xor(v, 1, 64);
      v += __shfl_xor(v, 2, 64);
      v += __shfl_xor(v, 4, 64);
      v += __shfl_xor(v, 8, 64);
      ls_[m][r] = v;
    }
  if (lr == 0) {
#pragma unroll
    for (int m = 0; m < 2; ++m)
#pragma unroll
      for (int r = 0; r < 4; ++r)
        lsl[wave][m * 16 + lg * 4 + r] = ls_[m][r];
  }
  __syncthreads();

  float inv0 = 1.f / (lsl[0][lr] + lsl[1][lr] + lsl[2][lr] + lsl[3][lr]);
  float inv1 = 1.f / (lsl[0][16 + lr] + lsl[1][16 + lr] + lsl[2][16 + lr] + lsl[3][16 + lr]);

  // O^T store: lane owns q=lr (accT0) / q=16+lr (accT1), dv = wave*16 + lg*4 + [0,4)
  short* ob0 = Obf + ((size_t)b * 1024 + qt * 32 + lr) * 512 + hd * 64 + wave * 16 + lg * 4;
  short* ob1 = Obf + ((size_t)b * 1024 + qt * 32 + 16 + lr) * 512 + hd * 64 + wave * 16 + lg * 4;
  *(unsigned*)(ob0)     = cvt_pk_bf16(accT0[0] * inv0, accT0[1] * inv0);
  *(unsigned*)(ob0 + 2) = cvt_pk_bf16(accT0[2] * inv0, accT0[3] * inv0);
  *(unsigned*)(ob1)     = cvt_pk_bf16(accT1[0] * inv1, accT1[1] * inv1);
  *(unsigned*)(ob1 + 2) = cvt_pk_bf16(accT1[2] * inv1, accT1[3] * inv1);
}

// ---------------- launch ----------------
extern "C" void kernel_launch(void* const* d_in, const int* in_sizes, int n_in,
                              void* d_out, int out_size, void* d_ws, size_t ws_size,
                              hipStream_t stream) {
  const float* x  = (const float*)d_in[0];
  const float* Wq = (const float*)d_in[1];
  const float* bq = (const float*)d_in[2];
  const float* Wk = (const float*)d_in[3];
  const float* bk = (const float*)d_in[4];
  const float* Wv = (const float*)d_in[5];
  const float* bv = (const float*)d_in[6];
  const float* Wo = (const float*)d_in[7];
  const float* bo = (const float*)d_in[8];
  float* out = (float*)d_out;
  float* ws  = (float*)d_ws;

  const size_t M1 = 1048576ull;  // 1M floats
  // ws layout (floats):
  short* xe_bf = (short*)ws;                 // [0, 1M)   4 MB; later dead -> Qbf
  short* Qbf   = (short*)ws;                 // reuse after QKV GEMMs
  short* Wqbf  = (short*)(ws + M1);          // [1M, 1.125M)
  short* Wkbf  = (short*)(ws + M1 + 131072);
  short* Wvbf  = (short*)(ws + M1 + 262144);
  short* Wobf  = (short*)(ws + M1 + 393216);
  float* Qb    = ws + M1 + 524288;           // [1.5M, 3.5M) fp32 8MB
  float* Kb    = Qb + 2 * M1;                // [3.5M, 5.5M)
  float* Vb    = Kb + 2 * M1;                // [5.5M, 7.5M)
  short* Vt    = (short*)Qb;                 // overlay Qb after epilogue (4MB)
  short* attn_out = (short*)Kb;              // overlay Kb after epilogue (4MB)
  // d_out scratch (all consumed before final GEMM):
  short* Kbf = (short*)out;                  // floats [0, 1M)
  float* bb  = out + M1;                     // 1040 floats
  float* q2h = out + M1 + 2048;              // 32768
  float* k2h = out + M1 + 2048 + 32768;      // 32768

  hipLaunchKernelGGL(prep_kernel, dim3(128, 5), dim3(256), 0, stream,
                     Wq, Wk, Wv, Wo, bq, bk, Wqbf, Wkbf, Wvbf, Wobf, bb);
  hipLaunchKernelGGL(logmap_kernel, dim3(4096), dim3(256), 0, stream, x, xe_bf);

  hipLaunchKernelGGL(gemm_qkv, dim3(8, 64, 3), dim3(256), 0, stream,
                     xe_bf, Wqbf, Wkbf, Wvbf, bv, Qb, Kb, Vb);

  hipLaunchKernelGGL(hyp_epilogue_v3, dim3(4096, 2), dim3(256), 0, stream,
                     Qb, Kb, bb, Qbf, Kbf, q2h, k2h);

  hipLaunchKernelGGL(vtrans_kernel, dim3(16, 8, 4), dim3(256), 0, stream, Vb, Vt);

  hipLaunchKernelGGL(attn_mfma, dim3(1024), dim3(256), 0, stream,
                     Qbf, Kbf, q2h, k2h, Vt, attn_out);

  hipLaunchKernelGGL(gemm_bf, dim3(8, 64), dim3(256), 0, stream, attn_out, Wobf, bo, out);
}

// Round 6
// 82.940 us; speedup vs baseline: 4.8409x; 1.1382x over previous
//
#include <hip/hip_runtime.h>
#include <math.h>

#define EPSF   1e-8f
#define CLAMPF 0.99999f   // 1 - 1e-5 (f32)

typedef __attribute__((ext_vector_type(8))) short bf16x8;
typedef __attribute__((ext_vector_type(4))) float f32x4;
#define MFMA16(a,b,c) __builtin_amdgcn_mfma_f32_16x16x32_bf16(a,b,c,0,0,0)

// hardware packed f32x2 -> bf16x2 (single VALU instr); low half = first arg
__device__ __forceinline__ unsigned cvt_pk_bf16(float lo, float hi) {
  unsigned r;
  asm("v_cvt_pk_bf16_f32 %0, %1, %2" : "=v"(r) : "v"(lo), "v"(hi));
  return r;
}

__device__ __forceinline__ float wave_sum64(float v) {
  v += __shfl_xor(v, 1, 64);
  v += __shfl_xor(v, 2, 64);
  v += __shfl_xor(v, 4, 64);
  v += __shfl_xor(v, 8, 64);
  v += __shfl_xor(v, 16, 64);
  v += __shfl_xor(v, 32, 64);
  return v;
}

// ---------------- fused prep: logmap (id<4096) + weight bf16 (4096..4607) + bias_ball (4608..4609) ----------------
__global__ __launch_bounds__(256) void prep_logmap(const float* __restrict__ x,
                                                   const float* __restrict__ Wq,
                                                   const float* __restrict__ Wk,
                                                   const float* __restrict__ Wv,
                                                   const float* __restrict__ Wo,
                                                   const float* __restrict__ bq,
                                                   const float* __restrict__ bk,
                                                   short* __restrict__ xe,
                                                   short* __restrict__ Wqbf,
                                                   short* __restrict__ Wkbf,
                                                   short* __restrict__ Wvbf,
                                                   short* __restrict__ Wobf,
                                                   float* __restrict__ bb) {
  const int id = blockIdx.x;
  const int t = threadIdx.x;
  __shared__ float red[4];
  if (id < 4096) {
    // xe = bf16(logmap0(x)), row id
    float2 v = ((const float2*)(x + (size_t)id * 512))[t];
    float s = wave_sum64(v.x * v.x + v.y * v.y);
    if ((t & 63) == 0) red[t >> 6] = s;
    __syncthreads();
    float n2 = red[0] + red[1] + red[2] + red[3];
    float n = sqrtf(n2);
    float nm = fmaxf(n, EPSF);
    float a = fminf(nm, 1.0f);
    float at = 0.5f * logf((1.f + a) / (1.f - a));
    float sc = at / nm;
    ((unsigned*)(xe + (size_t)id * 512))[t] = cvt_pk_bf16(v.x * sc, v.y * sc);
    return;
  }
  const int wid = id - 4096;
  if (wid < 512) {
    // weight fp32 -> bf16
    const int which = wid >> 7, chunk = wid & 127;
    const float* src; short* dst;
    switch (which) {
      case 0: src = Wq; dst = Wqbf; break;
      case 1: src = Wk; dst = Wkbf; break;
      case 2: src = Wv; dst = Wvbf; break;
      default: src = Wo; dst = Wobf; break;
    }
    const int idx = chunk * 2048 + t * 8;
    float4 a = *(const float4*)(src + idx);
    float4 b2 = *(const float4*)(src + idx + 4);
    union { int4 v; unsigned u[4]; } o;
    o.u[0] = cvt_pk_bf16(a.x, a.y);
    o.u[1] = cvt_pk_bf16(a.z, a.w);
    o.u[2] = cvt_pk_bf16(b2.x, b2.y);
    o.u[3] = cvt_pk_bf16(b2.z, b2.w);
    *(int4*)(dst + idx) = o.v;
    return;
  }
  // bias_ball = expmap0(b); 520 floats each
  const int which = wid - 512;
  const float* b = which ? bk : bq;
  float* o = bb + (size_t)which * 520;
  float2 v = ((const float2*)b)[t];
  float s = wave_sum64(v.x * v.x + v.y * v.y);
  if ((t & 63) == 0) red[t >> 6] = s;
  __syncthreads();
  float n2 = red[0] + red[1] + red[2] + red[3];
  float n = sqrtf(n2);
  float nm = fmaxf(n, EPSF);
  float tt = fminf(nm, 15.f);
  float f = tanhf(tt) / nm;
  float on = f * nm;
  if (on > CLAMPF) f *= CLAMPF / on;
  ((float2*)o)[t] = make_float2(f * v.x, f * v.y);
  if (t == 0) o[512] = f * f * n2;
}

// ---------------- bf16 MFMA GEMM core: out[m][n] = sum_k A[m][k] W[n][k] (+bias[n]) ----------------
// VT==0: fp32 out [4096][512]. VT==1: bf16 transposed out Vt[b][h][dv][t] with bias.
template <int VT>
__device__ __forceinline__ void gemm_core(const short* __restrict__ A,
                                          const short* __restrict__ W,
                                          const float* __restrict__ bias,
                                          void* __restrict__ outp,
                                          int bx, int by) {
  __shared__ __align__(16) short As[64][72];
  __shared__ __align__(16) short Ws[64][72];
  const int t = threadIdx.x;
  const int wave = t >> 6, lane = t & 63, lg = lane >> 4, lr = lane & 15;
  const int mh = wave & 1, nh = wave >> 1;
  f32x4 z = {0.f, 0.f, 0.f, 0.f};
  f32x4 acc00 = z, acc01 = z, acc10 = z, acc11 = z;
  const int srow = t >> 2, sc = (t & 3) * 16;
  const short* Ab = A + (size_t)(by * 64 + srow) * 512 + sc;
  const short* Wb = W + (size_t)(bx * 64 + srow) * 512 + sc;

  // prefetch tile 0
  int4 ra0 = *(const int4*)(Ab);
  int4 ra1 = *(const int4*)(Ab + 8);
  int4 rw0 = *(const int4*)(Wb);
  int4 rw1 = *(const int4*)(Wb + 8);

  for (int kt = 0; kt < 512; kt += 64) {
    __syncthreads();
    *(int4*)&As[srow][sc] = ra0;
    *(int4*)&As[srow][sc + 8] = ra1;
    *(int4*)&Ws[srow][sc] = rw0;
    *(int4*)&Ws[srow][sc + 8] = rw1;
    __syncthreads();
    if (kt < 448) {
      ra0 = *(const int4*)(Ab + kt + 64);
      ra1 = *(const int4*)(Ab + kt + 72);
      rw0 = *(const int4*)(Wb + kt + 64);
      rw1 = *(const int4*)(Wb + kt + 72);
    }
#pragma unroll
    for (int kk = 0; kk < 2; ++kk) {
      bf16x8 af0 = *(const bf16x8*)&As[mh * 32 + lr][kk * 32 + lg * 8];
      bf16x8 af1 = *(const bf16x8*)&As[mh * 32 + 16 + lr][kk * 32 + lg * 8];
      bf16x8 bf0 = *(const bf16x8*)&Ws[nh * 32 + lr][kk * 32 + lg * 8];
      bf16x8 bf1 = *(const bf16x8*)&Ws[nh * 32 + 16 + lr][kk * 32 + lg * 8];
      acc00 = MFMA16(af0, bf0, acc00);
      acc01 = MFMA16(af0, bf1, acc01);
      acc10 = MFMA16(af1, bf0, acc10);
      acc11 = MFMA16(af1, bf1, acc11);
    }
  }

  if (VT == 0) {
    float* out = (float*)outp;
    float b0 = 0.f, b1 = 0.f;
    if (bias) { b0 = bias[bx * 64 + nh * 32 + lr]; b1 = bias[bx * 64 + nh * 32 + 16 + lr]; }
#pragma unroll
    for (int r = 0; r < 4; ++r) {
      size_t row0 = (size_t)(by * 64 + mh * 32 + lg * 4 + r);
      size_t row1 = row0 + 16;
      out[row0 * 512 + bx * 64 + nh * 32 + lr] = acc00[r] + b0;
      out[row0 * 512 + bx * 64 + nh * 32 + 16 + lr] = acc01[r] + b1;
      out[row1 * 512 + bx * 64 + nh * 32 + lr] = acc10[r] + b0;
      out[row1 * 512 + bx * 64 + nh * 32 + 16 + lr] = acc11[r] + b1;
    }
  } else {
    // transposed bf16 store: Vt[(b*8 + c>>6)*64 + (c&63)][trow] = acc + bias[c]
    short* vt = (short*)outp;
    const int bidx = by >> 4;
    const int trow0 = (by & 15) * 64 + mh * 32 + lg * 4;
    const int c0 = bx * 64 + nh * 32 + lr;
    const int c1 = c0 + 16;
    const float b0 = bias[c0], b1 = bias[c1];
    size_t base0 = ((size_t)(bidx * 8 + (c0 >> 6)) * 64 + (c0 & 63)) * 1024;
    size_t base1 = ((size_t)(bidx * 8 + (c1 >> 6)) * 64 + (c1 & 63)) * 1024;
    uint2 pk;
    pk.x = cvt_pk_bf16(acc00[0] + b0, acc00[1] + b0);
    pk.y = cvt_pk_bf16(acc00[2] + b0, acc00[3] + b0);
    *(uint2*)(vt + base0 + trow0) = pk;
    pk.x = cvt_pk_bf16(acc01[0] + b1, acc01[1] + b1);
    pk.y = cvt_pk_bf16(acc01[2] + b1, acc01[3] + b1);
    *(uint2*)(vt + base1 + trow0) = pk;
    pk.x = cvt_pk_bf16(acc10[0] + b0, acc10[1] + b0);
    pk.y = cvt_pk_bf16(acc10[2] + b0, acc10[3] + b0);
    *(uint2*)(vt + base0 + trow0 + 16) = pk;
    pk.x = cvt_pk_bf16(acc11[0] + b1, acc11[1] + b1);
    pk.y = cvt_pk_bf16(acc11[2] + b1, acc11[3] + b1);
    *(uint2*)(vt + base1 + trow0 + 16) = pk;
  }
}

// batched QKV GEMM (grid.z selects); V path writes transposed bf16 Vt directly
__global__ __launch_bounds__(256) void gemm_qkv(const short* __restrict__ A,
                                                const short* __restrict__ Wq,
                                                const short* __restrict__ Wk,
                                                const short* __restrict__ Wv,
                                                const float* __restrict__ bv,
                                                float* __restrict__ Qo,
                                                float* __restrict__ Ko,
                                                short* __restrict__ Vt) {
  switch (blockIdx.z) {
    case 0: gemm_core<0>(A, Wq, nullptr, Qo, blockIdx.x, blockIdx.y); break;
    case 1: gemm_core<0>(A, Wk, nullptr, Ko, blockIdx.x, blockIdx.y); break;
    default: gemm_core<1>(A, Wv, bv, Vt, blockIdx.x, blockIdx.y); break;
  }
}

__global__ __launch_bounds__(256) void gemm_bf(const short* __restrict__ A,
                                               const short* __restrict__ W,
                                               const float* __restrict__ bias,
                                               float* __restrict__ out) {
  gemm_core<0>(A, W, bias, out, blockIdx.x, blockIdx.y);
}

// ---------------- hyperbolic epilogue (batched Q/K via grid.y) ----------------
// Ybf = bf16(mobius_add(expmap0(Y), bias_ball)); y2h[h][4096] per-head norms
__global__ __launch_bounds__(256) void hyp_epilogue_v3(const float* __restrict__ Qb,
                                                       const float* __restrict__ Kb,
                                                       const float* __restrict__ bbase,
                                                       short* __restrict__ Qbf,
                                                       short* __restrict__ Kbf,
                                                       float* __restrict__ q2h,
                                                       float* __restrict__ k2h) {
  const int row = blockIdx.x;
  const int which = blockIdx.y;
  const float* Y = which ? Kb : Qb;
  const float* bb = bbase + (size_t)which * 520;
  short* Ybf = which ? Kbf : Qbf;
  float* y2h = which ? k2h : q2h;
  const int t = threadIdx.x;
  float2 y = ((const float2*)(Y + (size_t)row * 512))[t];
  float2 w = ((const float2*)bb)[t];
  __shared__ float red[8];
  float sn = wave_sum64(y.x * y.x + y.y * y.y);
  float sd = wave_sum64(y.x * w.x + y.y * w.y);
  if ((t & 63) == 0) { red[t >> 6] = sn; red[4 + (t >> 6)] = sd; }
  __syncthreads();
  float n2 = red[0] + red[1] + red[2] + red[3];
  float dt = red[4] + red[5] + red[6] + red[7];
  float y2 = bb[512];
  float n = sqrtf(n2);
  float nm = fmaxf(n, EPSF);
  float tt = fminf(nm, 15.f);
  float f = tanhf(tt) / nm;
  float on = f * nm;
  if (on > CLAMPF) f *= CLAMPF / on;
  float x2 = f * f * n2;
  float xy = f * dt;
  float A = 1.f + 2.f * xy + y2;
  float Bc = 1.f - x2;
  float den = fmaxf(1.f + 2.f * xy + x2 * y2, EPSF);
  float num2 = A * A * x2 + Bc * Bc * y2 + 2.f * A * Bc * xy;
  float nn = sqrtf(fmaxf(num2, 0.f)) / den;
  float nnm = fmaxf(nn, EPSF);
  float s2 = (nnm > CLAMPF) ? (CLAMPF / nnm) : 1.f;
  float g = s2 / den;
  float ox = g * (A * f * y.x + Bc * w.x);
  float oy = g * (A * f * y.y + Bc * w.y);
  ((unsigned*)(Ybf + (size_t)row * 512))[t] = cvt_pk_bf16(ox, oy);
  // per-head norm in fp32 (head = t>>5)
  float hs = ox * ox + oy * oy;
  hs += __shfl_xor(hs, 1, 64);
  hs += __shfl_xor(hs, 2, 64);
  hs += __shfl_xor(hs, 4, 64);
  hs += __shfl_xor(hs, 8, 64);
  hs += __shfl_xor(hs, 16, 64);
  if ((t & 31) == 0) y2h[(size_t)(t >> 5) * 4096 + row] = hs;
}

// ---------------- MFMA flash attention ----------------
// Grid 1024 (1D, XCD-friendly decode), 256 threads = 4 waves.
// Swapped QK (mfma(K,Q)): lane owns queries {m*16+lr}, keys {wave*16+lg*4+r}.
// Register-prefetched K/V staging. Output bf16.
__global__ __launch_bounds__(256) void attn_mfma(const short* __restrict__ Qbf,
                                                 const short* __restrict__ Kbf,
                                                 const float* __restrict__ q2h,
                                                 const float* __restrict__ k2h,
                                                 const short* __restrict__ Vt,
                                                 short* __restrict__ Obf) {
  __shared__ __align__(16) short Qs[32][72];
  __shared__ __align__(16) short Ks[64][72];
  __shared__ __align__(16) short Vs[64][72];
  __shared__ __align__(16) short Ps[32][72];
  __shared__ float k2s[64];
  __shared__ float lsl[4][32];

  const int t = threadIdx.x;
  const int id = blockIdx.x;
  const int qt = id >> 5;
  const int pr = (((id >> 3) & 3) << 3) | (id & 7);
  const int hd = pr & 7, b = pr >> 3;

  const int wave = t >> 6, lane = t & 63, lg = lane >> 4, lr = lane & 15;
  const size_t hbase = (size_t)b * 1024 * 512 + (size_t)hd * 64;
  const size_t vtb = (size_t)(b * 8 + hd) * 64 * 1024;
  const int sr = t >> 3, sc8 = (t & 7) * 8;

  // stage Q (32 rows x 64 bf16)
  *(int4*)&Qs[sr][sc8] = *(const int4*)(Qbf + hbase + (size_t)(qt * 32 + sr) * 512 + sc8);
  __syncthreads();

  bf16x8 qf[2][2];
#pragma unroll
  for (int m = 0; m < 2; ++m)
#pragma unroll
    for (int kk = 0; kk < 2; ++kk)
      qf[m][kk] = *(const bf16x8*)&Qs[m * 16 + lr][kk * 32 + lg * 8];

  // per-lane query scalars (q = qt*32 + m*16 + lr)
  float q2m[2], bc2m[2], q2p1m2[2];
#pragma unroll
  for (int m = 0; m < 2; ++m) {
    float q2 = q2h[(size_t)hd * 4096 + b * 1024 + qt * 32 + m * 16 + lr];
    q2m[m] = q2;
    float bc = 1.f - q2;
    bc2m[m] = bc * bc;
    q2p1m2[m] = -2.f * (1.f + q2);
  }

  f32x4 z = {0.f, 0.f, 0.f, 0.f};
  f32x4 accT0 = z, accT1 = z;   // O^T fragments: q=lr (accT0), q=16+lr (accT1)
  float lsm[2] = {0.f, 0.f};

  const short* kp = Kbf + hbase + (size_t)sr * 512 + sc8;
  const short* vp = Vt + vtb + (size_t)sr * 1024 + sc8;
  const float* k2p = k2h + (size_t)hd * 4096 + b * 1024 + t;

  // prefetch tile 0 into registers
  int4 ka = *(const int4*)kp;
  int4 kb2 = *(const int4*)(kp + 32 * 512);
  int4 va = *(const int4*)vp;
  int4 vb2 = *(const int4*)(vp + 32 * 1024);
  float k2r = 0.f;
  if (t < 64) k2r = *k2p;

  for (int kt = 0; kt < 16; ++kt) {
    __syncthreads();  // (A) prior tile fully consumed
    *(int4*)&Ks[sr][sc8] = ka;
    *(int4*)&Ks[sr + 32][sc8] = kb2;
    *(int4*)&Vs[sr][sc8] = va;
    *(int4*)&Vs[sr + 32][sc8] = vb2;
    if (t < 64) k2s[t] = k2r;
    __syncthreads();  // (B) tiles staged
    if (kt < 15) {    // prefetch next tile; latency hides under QK+scores+PV
      kp += 64 * 512; vp += 64; k2p += 64;
      ka = *(const int4*)kp;
      kb2 = *(const int4*)(kp + 32 * 512);
      va = *(const int4*)vp;
      vb2 = *(const int4*)(vp + 32 * 1024);
      if (t < 64) k2r = *k2p;
    }

    // QK^T swapped: D[key][q]
    bf16x8 kf0 = *(const bf16x8*)&Ks[wave * 16 + lr][0 + lg * 8];
    bf16x8 kf1 = *(const bf16x8*)&Ks[wave * 16 + lr][32 + lg * 8];
    f32x4 s0 = z, s1 = z;
    s0 = MFMA16(kf0, qf[0][0], s0);
    s0 = MFMA16(kf1, qf[0][1], s0);
    s1 = MFMA16(kf0, qf[1][0], s1);
    s1 = MFMA16(kf1, qf[1][1], s1);

    // per-tile key scalars (4 keys per lane: wave*16 + lg*4 + r)
    float k2v[4], k2p1[4], k2p1sq[4];
#pragma unroll
    for (int r = 0; r < 4; ++r) {
      k2v[r] = k2s[wave * 16 + lg * 4 + r];
      k2p1[r] = 1.f + k2v[r];
      k2p1sq[r] = k2p1[r] * k2p1[r];
    }
#pragma unroll
    for (int m = 0; m < 2; ++m) {
      f32x4 sv = m ? s1 : s0;
      float p[4];
#pragma unroll
      for (int r = 0; r < 4; ++r) {
        float d = sv[r];
        // num2 = 4d^2 - 2(1+q2)(1+k2)d + q2(1+k2)^2 + (1-q2)^2 k2 ; den = 1 + q2 k2 - 2d
        float c1 = q2p1m2[m] * k2p1[r];
        float c0 = fmaf(q2m[m], k2p1sq[r], bc2m[m] * k2v[r]);
        float num2 = fmaf(d, fmaf(4.f, d, c1), c0);
        float den = fmaf(-2.f, d, fmaf(q2m[m], k2v[r], 1.f));
        num2 = fmaxf(num2, 0.f);
        den = fmaxf(den, EPSF);
        float sq = __builtin_amdgcn_sqrtf(num2);
        float u = (den - sq) * __builtin_amdgcn_rcpf(den + sq);
        u = fmaxf(u, 5.000025e-6f);   // n <= 0.99999 clamp
        p[r] = __builtin_amdgcn_exp2f(0.125f * __builtin_amdgcn_logf(u));
      }
      lsm[m] += (p[0] + p[1]) + (p[2] + p[3]);
      uint2 pk;
      pk.x = cvt_pk_bf16(p[0], p[1]);
      pk.y = cvt_pk_bf16(p[2], p[3]);
      *(uint2*)&Ps[m * 16 + lr][wave * 16 + lg * 4] = pk;   // 4 consecutive keys
    }
    __syncthreads();  // (C) P tile complete

    // PV swapped: accT = MFMA(V^T-frag, P-frag) -> O^T[dv][q]
    bf16x8 vf0 = *(const bf16x8*)&Vs[wave * 16 + lr][0 + lg * 8];
    bf16x8 vf1 = *(const bf16x8*)&Vs[wave * 16 + lr][32 + lg * 8];
    bf16x8 pa00 = *(const bf16x8*)&Ps[lr][0 + lg * 8];
    bf16x8 pa01 = *(const bf16x8*)&Ps[lr][32 + lg * 8];
    bf16x8 pa10 = *(const bf16x8*)&Ps[16 + lr][0 + lg * 8];
    bf16x8 pa11 = *(const bf16x8*)&Ps[16 + lr][32 + lg * 8];
    accT0 = MFMA16(vf0, pa00, accT0);
    accT0 = MFMA16(vf1, pa01, accT0);
    accT1 = MFMA16(vf0, pa10, accT1);
    accT1 = MFMA16(vf1, pa11, accT1);
  }

  // softmax denominators: lane holds partial for q=m*16+lr over its keys; sum across lg (xor 16,32)
#pragma unroll
  for (int m = 0; m < 2; ++m) {
    float v = lsm[m];
    v += __shfl_xor(v, 16, 64);
    v += __shfl_xor(v, 32, 64);
    lsm[m] = v;
  }
  if (lg == 0) {
    lsl[wave][lr] = lsm[0];
    lsl[wave][16 + lr] = lsm[1];
  }
  __syncthreads();

  float inv0 = 1.f / (lsl[0][lr] + lsl[1][lr] + lsl[2][lr] + lsl[3][lr]);
  float inv1 = 1.f / (lsl[0][16 + lr] + lsl[1][16 + lr] + lsl[2][16 + lr] + lsl[3][16 + lr]);

  // O^T store: lane owns q=lr (accT0) / q=16+lr (accT1), dv = wave*16 + lg*4 + [0,4)
  short* ob0 = Obf + ((size_t)b * 1024 + qt * 32 + lr) * 512 + hd * 64 + wave * 16 + lg * 4;
  short* ob1 = Obf + ((size_t)b * 1024 + qt * 32 + 16 + lr) * 512 + hd * 64 + wave * 16 + lg * 4;
  *(unsigned*)(ob0)     = cvt_pk_bf16(accT0[0] * inv0, accT0[1] * inv0);
  *(unsigned*)(ob0 + 2) = cvt_pk_bf16(accT0[2] * inv0, accT0[3] * inv0);
  *(unsigned*)(ob1)     = cvt_pk_bf16(accT1[0] * inv1, accT1[1] * inv1);
  *(unsigned*)(ob1 + 2) = cvt_pk_bf16(accT1[2] * inv1, accT1[3] * inv1);
}

// ---------------- launch ----------------
extern "C" void kernel_launch(void* const* d_in, const int* in_sizes, int n_in,
                              void* d_out, int out_size, void* d_ws, size_t ws_size,
                              hipStream_t stream) {
  const float* x  = (const float*)d_in[0];
  const float* Wq = (const float*)d_in[1];
  const float* bq = (const float*)d_in[2];
  const float* Wk = (const float*)d_in[3];
  const float* bk = (const float*)d_in[4];
  const float* Wv = (const float*)d_in[5];
  const float* bv = (const float*)d_in[6];
  const float* Wo = (const float*)d_in[7];
  const float* bo = (const float*)d_in[8];
  float* out = (float*)d_out;
  float* ws  = (float*)d_ws;

  const size_t M1 = 1048576ull;  // 1M floats
  // ws layout (float units). NOTE: every [4096][512] bf16 buffer = 2M shorts = 1M floats.
  //   Qb       [0,    2M)   fp32
  //   Kb       [2M,   4M)   fp32
  //   Vt       [4M,   5M)   2M bf16
  //   xe_bf    [5M,   6M)   2M bf16; dead after gemm_qkv -> reused as Qbf
  //   W*bf     [6M,   6.5M) 4 x 256K bf16
  //   attn_out [6.5M, 7.5M) 2M bf16
  // d_out scratch (2M floats total; all consumed before final GEMM writes out):
  //   Kbf      [0,    1M)   2M bf16
  //   bb       [1M,   1M+1040)
  //   q2h      [1M+2048, +32768)
  //   k2h      [1M+2048+32768, +32768)
  float* Qb    = ws;
  float* Kb    = ws + 2 * M1;
  short* Vt    = (short*)(ws + 4 * M1);
  short* xe_bf = (short*)(ws + 5 * M1);
  short* Qbf   = (short*)(ws + 5 * M1);      // reuse xe after gemm_qkv
  short* Wqbf  = (short*)(ws + 6 * M1);
  short* Wkbf  = (short*)(ws + 6 * M1 + 131072);
  short* Wvbf  = (short*)(ws + 6 * M1 + 262144);
  short* Wobf  = (short*)(ws + 6 * M1 + 393216);
  short* attn_out = (short*)(ws + 6 * M1 + 524288);
  short* Kbf = (short*)out;
  float* bb  = out + M1;
  float* q2h = out + M1 + 2048;
  float* k2h = out + M1 + 2048 + 32768;

  hipLaunchKernelGGL(prep_logmap, dim3(4610), dim3(256), 0, stream,
                     x, Wq, Wk, Wv, Wo, bq, bk, xe_bf, Wqbf, Wkbf, Wvbf, Wobf, bb);

  hipLaunchKernelGGL(gemm_qkv, dim3(8, 64, 3), dim3(256), 0, stream,
                     xe_bf, Wqbf, Wkbf, Wvbf, bv, Qb, Kb, Vt);

  hipLaunchKernelGGL(hyp_epilogue_v3, dim3(4096, 2), dim3(256), 0, stream,
                     Qb, Kb, bb, Qbf, Kbf, q2h, k2h);

  hipLaunchKernelGGL(attn_mfma, dim3(1024), dim3(256), 0, stream,
                     Qbf, Kbf, q2h, k2h, Vt, attn_out);

  hipLaunchKernelGGL(gemm_bf, dim3(8, 64), dim3(256), 0, stream, attn_out, Wobf, bo, out);
}